// Round 8
// baseline (984.300 us; speedup 1.0000x reference)
//
#include <hip/hip_runtime.h>
#include <hip/hip_bf16.h>
#include <math.h>

typedef __hip_bfloat16 bf16;
typedef float f32x4 __attribute__((ext_vector_type(4)));
typedef short bf16x8 __attribute__((ext_vector_type(8)));

#define NNODES 4095
#define BATCH 64
#define NUM_OPS 20
#define TEMP 3.0f

// workspace layout (bytes) — total 194 MiB
#define OFF_WTILE 0x000000ull              // interior B image: 1,638,400 B
#define OFF_WTL   0x190000ull              // leaf B image: 196,608 B
#define OFF_BIAS  0x1C0000ull              // 1280*4
#define OFF_HA    0x200000ull              // 64 MiB  (levels 11,9,7,...)
#define OFF_CA    (OFF_HA + (64ull<<20))   // 64 MiB
#define OFF_HB    (OFF_CA + (64ull<<20))   // 32 MiB  (levels 10,8,...,0)
#define OFF_CB    (OFF_HB + (32ull<<20))   // 32 MiB
#define OFF_XL    OFF_HB                   // leaf-x bf16 (32 MiB) aliases hB+cB

__device__ __forceinline__ float sigmoid_f(float x) {
    return 1.0f / (1.0f + __expf(-x));
}
__device__ __forceinline__ float tanh_f(float x) {
    return 1.0f - 2.0f / (__expf(2.0f * x) + 1.0f);
}

// direct global->LDS DMA, 16 B per lane; LDS dest = wave-uniform base + lane*16
__device__ __forceinline__ void async_copy16(const bf16* g, bf16* l) {
    __builtin_amdgcn_global_load_lds(
        (const __attribute__((address_space(1))) void*)g,
        (__attribute__((address_space(3))) void*)l,
        16, 0, 0);
}

// Pre-tile weights into exact per-(chblk,kb) LDS images.
// interior: wtile[chblk][kb10][chunk8][brow160][8]  (20480 B per tile)
// leaf:     wtL  [chblk][kb2 ][chunk8][brow96 ][8]  (12288 B per tile)
// brow = g*32 + cl, gates g: 0=i,1=o,2=u,3=f0,4=f1; ch = chblk*32+cl.
__global__ void init_weights(const float* __restrict__ Wiou,
                             const float* __restrict__ biou,
                             const float* __restrict__ Uiou,
                             const float* __restrict__ Wf,
                             const float* __restrict__ bfv,
                             const float* __restrict__ Uf,
                             bf16* __restrict__ wtile,
                             bf16* __restrict__ wtL,
                             float* __restrict__ biasCat)
{
    int idx = blockIdx.x * 256 + threadIdx.x;
    if (idx < 1280 * 640) {
        int k = idx % 640;
        int n = idx / 640;
        int g = n >> 8;
        int ch = n & 255;
        float v;
        if (k < 128) {
            v = (g < 3) ? Wiou[k * 768 + n] : Wf[k * 256 + ch];
        } else {
            int par = (k < 384) ? 0 : 1;
            int hh = (k - 128) & 255;
            if (g < 3) v = Uiou[(par * 256 + hh) * 768 + n];
            else {
                int kk = g - 3;
                v = Uf[(((kk * 2 + par) * 256) + hh) * 256 + ch];
            }
        }
        bf16 bv = __float2bfloat16(v);
        int chblk = (ch >> 5);
        int cl    = ch & 31;
        int kb    = k >> 6;
        int chunk = (k & 63) >> 3;
        int e     = k & 7;
        int brow  = g * 32 + cl;
        wtile[((size_t)(chblk * 10 + kb) * 8 + chunk) * 1280 + brow * 8 + e] = bv;
        if (k < 128 && g < 3)
            wtL[((size_t)(chblk * 2 + kb) * 8 + chunk) * 768 + brow * 8 + e] = bv;
    }
    if (idx < 1280) {
        biasCat[idx] = (idx < 768) ? biou[idx] : bfv[idx & 255];
    }
}

// Pre-convert leaf-level x (nodes 2047..4094) fp32 -> bf16, layout [b][j][128].
__global__ void convert_x(const float* __restrict__ arg_hot, bf16* __restrict__ xL)
{
    int t = blockIdx.x * 256 + threadIdx.x;
    int row = t >> 4;                            // b*2048 + j
    int ch0 = (t & 15) * 8;
    int b = row >> 11;
    int j = row & 2047;
    const float* src = arg_hot + ((size_t)b * NNODES + 2047 + j) * 128 + ch0;
    float4 a = *(const float4*)src;
    float4 c = *(const float4*)(src + 4);
    union { bf16x8 v; __hip_bfloat162 h2[4]; } u;
    u.h2[0] = __float22bfloat162_rn(make_float2(a.x, a.y));
    u.h2[1] = __float22bfloat162_rn(make_float2(a.z, a.w));
    u.h2[2] = __float22bfloat162_rn(make_float2(c.x, c.y));
    u.h2[3] = __float22bfloat162_rn(make_float2(c.z, c.w));
    *(bf16x8*)(xL + (size_t)t * 8) = u.v;
}

// One tree level. 512 threads = 8 waves = wr(2) x wc(2) x wg(2): gate-split
// wave specialization — wg0 owns gates {i,o,u}, wg1 owns {f0,f1} (leaf:
// {i,u}/{o}). Same 128x32 tile & LDS as before, 2x waves/CU for phase
// diversity. Double-buffered single-barrier K-loop. Epilogue: wg1 computes
// f0*c0+f1*c1 (+c loads), passes via 16 KB LDS exchange; wg0 finishes cell.
template <bool LEAF>
__global__ __launch_bounds__(512, 4)
void level_kernel(const float* __restrict__ arg_hot,
                  const bf16* __restrict__ wt,
                  const float* __restrict__ biasCat,
                  const bf16* __restrict__ xL,        // leaf only
                  const bf16* __restrict__ h_child,   // [(2M) rows][256]
                  const bf16* __restrict__ c_child,
                  bf16* __restrict__ h_out,           // [M rows][256]
                  bf16* __restrict__ c_out,
                  int m, int logm)
{
    constexpr int KI  = LEAF ? 2 : 10;    // k-blocks of 64
    constexpr int BR  = LEAF ? 96 : 160;  // B rows per image tile
    constexpr int BI  = LEAF ? 12 : 20;   // B DMA instrs per kb (block total)
    constexpr int NG0 = LEAF ? 2 : 3;     // gates owned by wg0
    constexpr int NG1 = LEAF ? 1 : 2;     // gates owned by wg1

    const int M = BATCH * m;
    const int node_base = m - 1;

    __shared__ bf16 As[2][128 * 64];     // 2 x 16 KB
    __shared__ bf16 Bs[2][8 * BR * 8];   // 2 x (20 KB / 12 KB)

    const int tid = threadIdx.x;

    // block swizzle: the 8 ch-blocks sharing an A m-tile land consecutive on one XCD
    int bid = blockIdx.x;
    int mtiles = gridDim.x >> 3;
    int mtile, chblk;
    if ((mtiles & 7) == 0) {
        int xcd = bid & 7;
        int seq = bid >> 3;
        chblk = seq & 7;
        mtile = ((seq >> 3) << 3) + xcd;
    } else {
        mtile = bid >> 3;
        chblk = bid & 7;
    }
    const int rbase  = mtile * 128;
    const int chbase = chblk * 32;

    const int lane = tid & 63;
    const int wave = tid >> 6;
    const int wr = wave & 1;          // row half (64 rows)
    const int wc = (wave >> 1) & 1;   // channel half (16 ch)
    const int wg = wave >> 2;         // gate group
    const int l15 = lane & 15;
    const int lq  = lane >> 4;
    const int xr7 = l15 & 7;          // fragment-read XOR key

    f32x4 acc[4][3];
#pragma unroll
    for (int a = 0; a < 4; ++a)
#pragma unroll
        for (int g = 0; g < 3; ++g)
            acc[a][g] = (f32x4){0.f, 0.f, 0.f, 0.f};

    // A-DMA lane constants: instr t covers rows t*8..t*8+7, full 128-B k-line
    const int row_l = lane >> 3;
    const int cc_l  = lane & 7;
    const int aoffH = row_l * 512 + (cc_l ^ row_l) * 8;   // h rows: 512 elems
    const int aoffX = row_l * 128 + (cc_l ^ row_l) * 8;   // x rows: 128 elems

    const bf16* wbase = wt + (size_t)chblk * KI * (BR * 64);

    // x staging source row for interior kb<2 (clamped for partial tiles)
    const int arow = tid & 127;
    const int rs = min(rbase + arow, M - 1);
    const float* xrow = LEAF ? nullptr : arg_hot +
        ((size_t)(rs >> logm) * NNODES + node_base + (rs & (m - 1))) * 128;
    const int xswz_base = arow * 64;
    const int ar7 = arow & 7;

    const bf16* xLbase = LEAF ? xL + (size_t)rbase * 128 + aoffX : nullptr;

    // ---- staging: issue DMA / conversion writes for k-block kb into buf ----
    auto stage = [&](int kb, int buf) {
        bf16* Ab = As[buf];
        bf16* Bb = Bs[buf];
        if (LEAF) {
            const bf16* xb = xLbase + kb * 64;
#pragma unroll
            for (int jj = 0; jj < 2; ++jj) {
                int t = wave * 2 + jj;
                async_copy16(xb + t * 1024, &Ab[t * 512]);
            }
        } else if (kb < 2) {
            const float* xk = xrow + kb * 64;
#pragma unroll
            for (int jj = 0; jj < 2; ++jj) {
                int chunk = (tid >> 7) + 4 * jj;
                const float* src = xk + chunk * 8;
                float4 a = *(const float4*)src;
                float4 b = *(const float4*)(src + 4);
                union { int4 i4; __hip_bfloat162 h2[4]; } u;
                u.h2[0] = __float22bfloat162_rn(make_float2(a.x, a.y));
                u.h2[1] = __float22bfloat162_rn(make_float2(a.z, a.w));
                u.h2[2] = __float22bfloat162_rn(make_float2(b.x, b.y));
                u.h2[3] = __float22bfloat162_rn(make_float2(b.z, b.w));
                *(int4*)&Ab[xswz_base + ((chunk ^ ar7) * 8)] = u.i4;
            }
        } else {
            const bf16* hb = h_child + (size_t)rbase * 512 + (kb * 64 - 128) + aoffH;
#pragma unroll
            for (int jj = 0; jj < 2; ++jj) {
                int t = wave * 2 + jj;
                async_copy16(hb + t * 8 * 512, &Ab[t * 512]);
            }
        }
        const bf16* bsrc = wbase + (size_t)kb * (BR * 64);
        for (int j = wave; j < BI; j += 8)
            async_copy16(bsrc + j * 512 + lane * 8, &Bb[j * 512]);
    };

    stage(0, 0);

    for (int kb = 0; kb < KI; ++kb) {
        int buf = kb & 1;
        __syncthreads();     // drains DMA(kb) issued a full compute phase ago
        if (kb + 1 < KI) stage(kb + 1, buf ^ 1);
        // ---- compute: 2 k-steps of 32; per-wave gate subset ----
#pragma unroll
        for (int ks = 0; ks < 2; ++ks) {
            int q = ks * 4 + lq;
            int qa = (q ^ xr7) * 8;
            bf16x8 af[4];
#pragma unroll
            for (int rt = 0; rt < 4; ++rt)
                af[rt] = *(const bf16x8*)&As[buf][(wr * 64 + rt * 16 + l15) * 64 + qa];
            if (wg == 0) {
#pragma unroll
                for (int gi = 0; gi < NG0; ++gi) {
                    int g = LEAF ? gi * 2 : gi;          // leaf {0,2}, interior {0,1,2}
                    bf16x8 bfr = *(const bf16x8*)&Bs[buf][q * (BR * 8) + (g * 32 + wc * 16 + l15) * 8];
#pragma unroll
                    for (int rt = 0; rt < 4; ++rt)
                        acc[rt][gi] = __builtin_amdgcn_mfma_f32_16x16x32_bf16(
                            af[rt], bfr, acc[rt][gi], 0, 0, 0);
                }
            } else {
#pragma unroll
                for (int gi = 0; gi < NG1; ++gi) {
                    int g = LEAF ? 1 : 3 + gi;           // leaf {1}, interior {3,4}
                    bf16x8 bfr = *(const bf16x8*)&Bs[buf][q * (BR * 8) + (g * 32 + wc * 16 + l15) * 8];
#pragma unroll
                    for (int rt = 0; rt < 4; ++rt)
                        acc[rt][gi] = __builtin_amdgcn_mfma_f32_16x16x32_bf16(
                            af[rt], bfr, acc[rt][gi], 0, 0, 0);
                }
            }
        }
    }

    // ---- split epilogue with LDS handoff (reuses As[0]; last kb used buf 1) ----
    const int ch = chbase + wc * 16 + l15;
    float* fs = (float*)(&As[0][0]);                 // 4096 f32 = 16 KB
    const int sbase = (wr * 2 + wc) * 64 + lane;

    if (!LEAF) {
        if (wg == 1) {
            const float b_f = biasCat[768 + ch];
#pragma unroll
            for (int rt = 0; rt < 4; ++rt)
#pragma unroll
                for (int ri = 0; ri < 4; ++ri) {
                    int r = rbase + wr * 64 + rt * 16 + lq * 4 + ri;
                    float v = 0.f;
                    if (r < M) {
                        float f0 = sigmoid_f(acc[rt][0][ri] + b_f);
                        float f1 = sigmoid_f(acc[rt][1][ri] + b_f);
                        float c0 = __bfloat162float(c_child[(size_t)r * 512 + ch]);
                        float c1 = __bfloat162float(c_child[(size_t)r * 512 + 256 + ch]);
                        v = f0 * c0 + f1 * c1;
                    }
                    fs[(rt * 4 + ri) * 256 + sbase] = v;
                }
        }
        __syncthreads();
        if (wg == 0) {
            const float b_i = biasCat[ch];
            const float b_o = biasCat[256 + ch];
            const float b_u = biasCat[512 + ch];
#pragma unroll
            for (int rt = 0; rt < 4; ++rt)
#pragma unroll
                for (int ri = 0; ri < 4; ++ri) {
                    int r = rbase + wr * 64 + rt * 16 + lq * 4 + ri;
                    if (r < M) {
                        float i = sigmoid_f(acc[rt][0][ri] + b_i);
                        float o = sigmoid_f(acc[rt][1][ri] + b_o);
                        float u = tanh_f(acc[rt][2][ri] + b_u);
                        float cn = i * u + fs[(rt * 4 + ri) * 256 + sbase];
                        float h = o * tanh_f(cn);
                        h_out[(size_t)r * 256 + ch] = __float2bfloat16(h);
                        c_out[(size_t)r * 256 + ch] = __float2bfloat16(cn);
                    }
                }
        }
    } else {
        if (wg == 0) {
            const float b_i = biasCat[ch];
            const float b_u = biasCat[512 + ch];
#pragma unroll
            for (int rt = 0; rt < 4; ++rt)
#pragma unroll
                for (int ri = 0; ri < 4; ++ri) {
                    int r = rbase + wr * 64 + rt * 16 + lq * 4 + ri;
                    float cn = 0.f;
                    if (r < M) {
                        float i = sigmoid_f(acc[rt][0][ri] + b_i);
                        float u = tanh_f(acc[rt][1][ri] + b_u);
                        cn = i * u;
                        c_out[(size_t)r * 256 + ch] = __float2bfloat16(cn);
                    }
                    fs[(rt * 4 + ri) * 256 + sbase] = cn;
                }
        }
        __syncthreads();
        if (wg == 1) {
            const float b_o = biasCat[256 + ch];
#pragma unroll
            for (int rt = 0; rt < 4; ++rt)
#pragma unroll
                for (int ri = 0; ri < 4; ++ri) {
                    int r = rbase + wr * 64 + rt * 16 + lq * 4 + ri;
                    if (r < M) {
                        float o = sigmoid_f(acc[rt][0][ri] + b_o);
                        float cn = fs[(rt * 4 + ri) * 256 + sbase];
                        float h = o * tanh_f(cn);
                        h_out[(size_t)r * 256 + ch] = __float2bfloat16(h);
                    }
                }
        }
    }
}

// actor head: logits = log(mask) + (h.w + b)*mask; softmax(logits/TEMP)
__global__ void head_kernel(const bf16* __restrict__ rootH,
                            const float* __restrict__ actor_w,
                            const float* __restrict__ actor_b,
                            const float* __restrict__ vmask,
                            float* __restrict__ out)
{
    int b = blockIdx.x;
    __shared__ float logits[NUM_OPS];
    int t = threadIdx.x;
    if (t < NUM_OPS) {
        const bf16* hr = rootH + b * 256;
        const float* w = actor_w + t * 256;
        float dot = 0.f;
        for (int hh = 0; hh < 256; ++hh)
            dot += __bfloat162float(hr[hh]) * w[hh];
        float mk = vmask[b * NUM_OPS + t];
        float lg = (mk > 0.f) ? (logf(mk) + (dot + actor_b[t]) * mk) : -INFINITY;
        logits[t] = lg / TEMP;
    }
    __syncthreads();
    if (t == 0) {
        float mx = -INFINITY;
        for (int o = 0; o < NUM_OPS; ++o) mx = fmaxf(mx, logits[o]);
        float s = 0.f;
        float e[NUM_OPS];
        for (int o = 0; o < NUM_OPS; ++o) { e[o] = __expf(logits[o] - mx); s += e[o]; }
        float inv = 1.f / s;
        for (int o = 0; o < NUM_OPS; ++o) out[b * NUM_OPS + o] = e[o] * inv;
    }
}

extern "C" void kernel_launch(void* const* d_in, const int* in_sizes, int n_in,
                              void* d_out, int out_size, void* d_ws, size_t ws_size,
                              hipStream_t stream)
{
    const float* arg_hot = (const float*)d_in[0];
    const float* Wiou    = (const float*)d_in[1];
    const float* biou    = (const float*)d_in[2];
    const float* Uiou    = (const float*)d_in[3];
    const float* Wf      = (const float*)d_in[4];
    const float* bfv     = (const float*)d_in[5];
    const float* Uf      = (const float*)d_in[6];
    const float* actor_w = (const float*)d_in[7];
    const float* actor_b = (const float*)d_in[8];
    const float* vmask   = (const float*)d_in[9];

    char* ws = (char*)d_ws;
    bf16*  wtile   = (bf16*)(ws + OFF_WTILE);
    bf16*  wtL     = (bf16*)(ws + OFF_WTL);
    float* biasCat = (float*)(ws + OFF_BIAS);
    bf16*  hA = (bf16*)(ws + OFF_HA);
    bf16*  cA = (bf16*)(ws + OFF_CA);
    bf16*  hB = (bf16*)(ws + OFF_HB);
    bf16*  cB = (bf16*)(ws + OFF_CB);
    bf16*  xL = (bf16*)(ws + OFF_XL);   // aliases hB+cB (dead until L10)

    init_weights<<<dim3((1280 * 640 + 255) / 256), 256, 0, stream>>>(
        Wiou, biou, Uiou, Wf, bfv, Uf, wtile, wtL, biasCat);
    convert_x<<<dim3(8192), 256, 0, stream>>>(arg_hot, xL);

    // leaf level (l=11): m=2048, K=128, reads xL, writes buffers A
    {
        int m = 2048;
        int mtiles = (BATCH * m + 127) / 128;   // 1024
        level_kernel<true><<<dim3(mtiles * 8), 512, 0, stream>>>(
            arg_hot, wtL, biasCat, xL, nullptr, nullptr, hA, cA, m, 11);
    }
    // interior levels 10..0
    for (int l = 10; l >= 0; --l) {
        int m = 1 << l;
        int mtiles = (BATCH * m + 127) / 128;
        bf16 *hc, *cc, *ho, *co;
        if (l & 1) { hc = hB; cc = cB; ho = hA; co = cA; }
        else       { hc = hA; cc = cA; ho = hB; co = cB; }
        level_kernel<false><<<dim3(mtiles * 8), 512, 0, stream>>>(
            arg_hot, wtile, biasCat, nullptr, hc, cc, ho, co, m, l);
    }
    // root h is in hB (level 0 writes B)
    head_kernel<<<dim3(BATCH), 64, 0, stream>>>(hB, actor_w, actor_b, vmask, (float*)d_out);
}

// Round 9
// 802.413 us; speedup vs baseline: 1.2267x; 1.2267x over previous
//
#include <hip/hip_runtime.h>
#include <hip/hip_bf16.h>
#include <math.h>

typedef __hip_bfloat16 bf16;
typedef float f32x4 __attribute__((ext_vector_type(4)));
typedef short bf16x8 __attribute__((ext_vector_type(8)));

#define NNODES 4095
#define BATCH 64
#define NUM_OPS 20
#define TEMP 3.0f

// workspace layout (bytes) — total 194 MiB
#define OFF_WTILE 0x000000ull              // interior B image: 1,638,400 B
#define OFF_WTL   0x190000ull              // leaf B image: 196,608 B
#define OFF_BIAS  0x1C0000ull              // 1280*4
#define OFF_HA    0x200000ull              // 64 MiB  (levels 11,9,7,...)
#define OFF_CA    (OFF_HA + (64ull<<20))   // 64 MiB
#define OFF_HB    (OFF_CA + (64ull<<20))   // 32 MiB  (levels 10,8,...,0)
#define OFF_CB    (OFF_HB + (32ull<<20))   // 32 MiB
#define OFF_XL    OFF_HB                   // leaf-x bf16 (32 MiB) aliases hB+cB

__device__ __forceinline__ float sigmoid_f(float x) {
    return 1.0f / (1.0f + __expf(-x));
}
__device__ __forceinline__ float tanh_f(float x) {
    return 1.0f - 2.0f / (__expf(2.0f * x) + 1.0f);
}

// direct global->LDS DMA, 16 B per lane; LDS dest = wave-uniform base + lane*16
__device__ __forceinline__ void async_copy16(const bf16* g, bf16* l) {
    __builtin_amdgcn_global_load_lds(
        (const __attribute__((address_space(1))) void*)g,
        (__attribute__((address_space(3))) void*)l,
        16, 0, 0);
}

// Pre-tile weights into exact per-(chblk,kb) LDS images, BK=32.
// interior: wtile[chblk][kb20][chunk4][brow160][8]  (10240 B per tile)
// leaf:     wtL  [chblk][kb4 ][chunk4][brow96 ][8]  ( 6144 B per tile)
// brow = g*32 + cl, gates g: 0=i,1=o,2=u,3=f0,4=f1; ch = chblk*32+cl.
// k<128: x rows (Wiou | Wf dup); k in [128,384): even child; [384,640): odd.
__global__ void init_weights(const float* __restrict__ Wiou,
                             const float* __restrict__ biou,
                             const float* __restrict__ Uiou,
                             const float* __restrict__ Wf,
                             const float* __restrict__ bfv,
                             const float* __restrict__ Uf,
                             bf16* __restrict__ wtile,
                             bf16* __restrict__ wtL,
                             float* __restrict__ biasCat)
{
    int idx = blockIdx.x * 256 + threadIdx.x;
    if (idx < 1280 * 640) {
        int k = idx % 640;
        int n = idx / 640;
        int g = n >> 8;
        int ch = n & 255;
        float v;
        if (k < 128) {
            v = (g < 3) ? Wiou[k * 768 + n] : Wf[k * 256 + ch];
        } else {
            int par = (k < 384) ? 0 : 1;
            int hh = (k - 128) & 255;
            if (g < 3) v = Uiou[(par * 256 + hh) * 768 + n];
            else {
                int kk = g - 3;
                v = Uf[(((kk * 2 + par) * 256) + hh) * 256 + ch];
            }
        }
        bf16 bv = __float2bfloat16(v);
        int chblk = (ch >> 5);
        int cl    = ch & 31;
        int kb    = k >> 5;           // 0..19
        int chunk = (k & 31) >> 3;    // 0..3
        int e     = k & 7;
        int brow  = g * 32 + cl;
        wtile[((size_t)(chblk * 20 + kb) * 4 + chunk) * 1280 + brow * 8 + e] = bv;
        if (k < 128 && g < 3)
            wtL[((size_t)(chblk * 4 + kb) * 4 + chunk) * 768 + brow * 8 + e] = bv;
    }
    if (idx < 1280) {
        biasCat[idx] = (idx < 768) ? biou[idx] : bfv[idx & 255];
    }
}

// Pre-convert leaf-level x (nodes 2047..4094) fp32 -> bf16, layout [b][j][128].
__global__ void convert_x(const float* __restrict__ arg_hot, bf16* __restrict__ xL)
{
    int t = blockIdx.x * 256 + threadIdx.x;
    int row = t >> 4;                            // b*2048 + j
    int ch0 = (t & 15) * 8;
    int b = row >> 11;
    int j = row & 2047;
    const float* src = arg_hot + ((size_t)b * NNODES + 2047 + j) * 128 + ch0;
    float4 a = *(const float4*)src;
    float4 c = *(const float4*)(src + 4);
    union { bf16x8 v; __hip_bfloat162 h2[4]; } u;
    u.h2[0] = __float22bfloat162_rn(make_float2(a.x, a.y));
    u.h2[1] = __float22bfloat162_rn(make_float2(a.z, a.w));
    u.h2[2] = __float22bfloat162_rn(make_float2(c.x, c.y));
    u.h2[3] = __float22bfloat162_rn(make_float2(c.z, c.w));
    *(bf16x8*)(xL + (size_t)t * 8) = u.v;
}

// One tree level. BK=32 double-buffered single-barrier K-loop: 36 KB LDS
// (leaf 28 KB) -> 4 blocks/CU resident, each phase drains a DMA issued one
// full compute phase earlier. Block tile: 128 rows x 32 ch x NG gates;
// fused LSTM epilogue. A LDS: [row][chunk^((row>>1)&3)][8] (bank-even DMA,
// fragment reads, and convert-writes). B LDS: linear image copy.
template <bool LEAF>
__global__ __launch_bounds__(256, 4)
void level_kernel(const float* __restrict__ arg_hot,
                  const bf16* __restrict__ wt,
                  const float* __restrict__ biasCat,
                  const bf16* __restrict__ xL,        // leaf only
                  const bf16* __restrict__ h_child,   // [(2M) rows][256]
                  const bf16* __restrict__ c_child,
                  bf16* __restrict__ h_out,           // [M rows][256]
                  bf16* __restrict__ c_out,
                  int m, int logm)
{
    constexpr int NG  = LEAF ? 3 : 5;
    constexpr int KI  = LEAF ? 4 : 20;    // k-blocks of 32
    constexpr int BR  = LEAF ? 96 : 160;  // B rows per image tile
    constexpr int BI  = LEAF ? 6 : 10;    // B DMA instrs per kb (block total)

    const int M = BATCH * m;
    const int node_base = m - 1;

    __shared__ bf16 As[2][128 * 32];     // 2 x 8 KB
    __shared__ bf16 Bs[2][4 * BR * 8];   // 2 x (10 KB / 6 KB)

    const int tid = threadIdx.x;

    // block swizzle: the 8 ch-blocks sharing an A m-tile land consecutive on one XCD
    int bid = blockIdx.x;
    int mtiles = gridDim.x >> 3;
    int mtile, chblk;
    if ((mtiles & 7) == 0) {
        int xcd = bid & 7;
        int seq = bid >> 3;
        chblk = seq & 7;
        mtile = ((seq >> 3) << 3) + xcd;
    } else {
        mtile = bid >> 3;
        chblk = bid & 7;
    }
    const int rbase  = mtile * 128;
    const int chbase = chblk * 32;

    const int lane = tid & 63;
    const int wave = tid >> 6;
    const int wr = wave & 1;   // row half (64 rows)
    const int wc = wave >> 1;  // channel half (16 ch)
    const int l15 = lane & 15;
    const int lq  = lane >> 4;
    const int xr3 = (l15 >> 1) & 3;   // fragment-read XOR key

    f32x4 acc[4][NG];
#pragma unroll
    for (int a = 0; a < 4; ++a)
#pragma unroll
        for (int g = 0; g < NG; ++g)
            acc[a][g] = (f32x4){0.f, 0.f, 0.f, 0.f};

    // A-DMA lane constants: instr t covers rows t*16..t*16+15, full 64-B k-line.
    // lane -> row = t*16 + (lane>>2), chunk_lds = lane&3,
    // logical chunk = (lane&3) ^ (((lane>>2)>>1)&3)  (t*16 contributes 0 to key)
    const int l4 = lane >> 2;
    const int c4 = lane & 3;
    const int akey  = (l4 >> 1) & 3;
    const int aoffH = l4 * 512 + (c4 ^ akey) * 8;   // h rows: 512 elems
    const int aoffX = l4 * 128 + (c4 ^ akey) * 8;   // xL rows: 128 elems

    const bf16* wbase = wt + (size_t)chblk * KI * (BR * 32);

    // x staging source row for interior kb<4 (clamped for partial tiles)
    const int arow = tid & 127;
    const int rs = min(rbase + arow, M - 1);
    const float* xrow = LEAF ? nullptr : arg_hot +
        ((size_t)(rs >> logm) * NNODES + node_base + (rs & (m - 1))) * 128;
    const int ar3 = (arow >> 1) & 3;

    const bf16* xLbase = LEAF ? xL + (size_t)rbase * 128 + aoffX : nullptr;

    // ---- staging: issue DMA / conversion writes for k-block kb into buf ----
    auto stage = [&](int kb, int buf) {
        bf16* Ab = As[buf];
        bf16* Bb = Bs[buf];
        if (LEAF) {
            const bf16* xb = xLbase + kb * 32;
#pragma unroll
            for (int i = 0; i < 2; ++i) {
                int t = wave * 2 + i;                 // 0..7, rows t*16..+15
                async_copy16(xb + t * 2048, &Ab[t * 512]);
            }
        } else if (kb < 4) {
            // x region: fp32 -> bf16 packed converts, swizzled b128 LDS writes
            const float* xk = xrow + kb * 32;
#pragma unroll
            for (int j = 0; j < 2; ++j) {
                int c = (tid >> 7) + 2 * j;           // chunks {0,2} or {1,3}
                const float* src = xk + c * 8;
                float4 a = *(const float4*)src;
                float4 b = *(const float4*)(src + 4);
                union { int4 i4; __hip_bfloat162 h2[4]; } u;
                u.h2[0] = __float22bfloat162_rn(make_float2(a.x, a.y));
                u.h2[1] = __float22bfloat162_rn(make_float2(a.z, a.w));
                u.h2[2] = __float22bfloat162_rn(make_float2(b.x, b.y));
                u.h2[3] = __float22bfloat162_rn(make_float2(b.z, b.w));
                *(int4*)&Ab[arow * 32 + ((c ^ ar3) * 8)] = u.i4;
            }
        } else {
            // h region: DMA; each instr = 16 rows x one full 64-B k-line
            const bf16* hb = h_child + (size_t)rbase * 512 + (kb * 32 - 128) + aoffH;
#pragma unroll
            for (int i = 0; i < 2; ++i) {
                int t = wave * 2 + i;
                async_copy16(hb + (size_t)t * 16 * 512, &Ab[t * 512]);
            }
        }
        // B: linear DMA of the pre-tiled image (BI instrs, round-robin waves)
        const bf16* bsrc = wbase + (size_t)kb * (BR * 32);
        for (int j = wave; j < BI; j += 4)
            async_copy16(bsrc + j * 512 + lane * 8, &Bb[j * 512]);
    };

    stage(0, 0);

    for (int kb = 0; kb < KI; ++kb) {
        int buf = kb & 1;
        __syncthreads();     // drains DMA(kb) issued one full compute phase ago
        if (kb + 1 < KI) stage(kb + 1, buf ^ 1);
        // ---- compute: one k-step of 32, 4 x NG MFMAs ----
        bf16x8 af[4];
#pragma unroll
        for (int rt = 0; rt < 4; ++rt)
            af[rt] = *(const bf16x8*)&As[buf][(wr * 64 + rt * 16 + l15) * 32 + ((lq ^ xr3) * 8)];
#pragma unroll
        for (int g = 0; g < NG; ++g) {
            bf16x8 bfr = *(const bf16x8*)&Bs[buf][lq * (BR * 8) + (g * 32 + wc * 16 + l15) * 8];
#pragma unroll
            for (int rt = 0; rt < 4; ++rt)
                acc[rt][g] = __builtin_amdgcn_mfma_f32_16x16x32_bf16(
                    af[rt], bfr, acc[rt][g], 0, 0, 0);
        }
    }

    // ---- fused LSTM-cell epilogue (all gates in-register per lane) ----
    const int ch = chbase + wc * 16 + l15;
    const float b_i = biasCat[ch];
    const float b_o = biasCat[256 + ch];
    const float b_u = biasCat[512 + ch];
    const float b_f = LEAF ? 0.f : biasCat[768 + ch];

#pragma unroll
    for (int rt = 0; rt < 4; ++rt) {
#pragma unroll
        for (int ri = 0; ri < 4; ++ri) {
            int r = rbase + wr * 64 + rt * 16 + lq * 4 + ri;
            if (r < M) {
                float i = sigmoid_f(acc[rt][0][ri] + b_i);
                float o = sigmoid_f(acc[rt][1][ri] + b_o);
                float u = tanh_f(acc[rt][2][ri] + b_u);
                float cn;
                if (LEAF) {
                    cn = i * u;
                } else {
                    float f0 = sigmoid_f(acc[rt][3][ri] + b_f);
                    float f1 = sigmoid_f(acc[rt][4][ri] + b_f);
                    float c0 = __bfloat162float(c_child[(size_t)r * 512 + ch]);
                    float c1 = __bfloat162float(c_child[(size_t)r * 512 + 256 + ch]);
                    cn = i * u + f0 * c0 + f1 * c1;
                }
                float h = o * tanh_f(cn);
                h_out[(size_t)r * 256 + ch] = __float2bfloat16(h);
                c_out[(size_t)r * 256 + ch] = __float2bfloat16(cn);
            }
        }
    }
}

// actor head: logits = log(mask) + (h.w + b)*mask; softmax(logits/TEMP)
__global__ void head_kernel(const bf16* __restrict__ rootH,
                            const float* __restrict__ actor_w,
                            const float* __restrict__ actor_b,
                            const float* __restrict__ vmask,
                            float* __restrict__ out)
{
    int b = blockIdx.x;
    __shared__ float logits[NUM_OPS];
    int t = threadIdx.x;
    if (t < NUM_OPS) {
        const bf16* hr = rootH + b * 256;
        const float* w = actor_w + t * 256;
        float dot = 0.f;
        for (int hh = 0; hh < 256; ++hh)
            dot += __bfloat162float(hr[hh]) * w[hh];
        float mk = vmask[b * NUM_OPS + t];
        float lg = (mk > 0.f) ? (logf(mk) + (dot + actor_b[t]) * mk) : -INFINITY;
        logits[t] = lg / TEMP;
    }
    __syncthreads();
    if (t == 0) {
        float mx = -INFINITY;
        for (int o = 0; o < NUM_OPS; ++o) mx = fmaxf(mx, logits[o]);
        float s = 0.f;
        float e[NUM_OPS];
        for (int o = 0; o < NUM_OPS; ++o) { e[o] = __expf(logits[o] - mx); s += e[o]; }
        float inv = 1.f / s;
        for (int o = 0; o < NUM_OPS; ++o) out[b * NUM_OPS + o] = e[o] * inv;
    }
}

extern "C" void kernel_launch(void* const* d_in, const int* in_sizes, int n_in,
                              void* d_out, int out_size, void* d_ws, size_t ws_size,
                              hipStream_t stream)
{
    const float* arg_hot = (const float*)d_in[0];
    const float* Wiou    = (const float*)d_in[1];
    const float* biou    = (const float*)d_in[2];
    const float* Uiou    = (const float*)d_in[3];
    const float* Wf      = (const float*)d_in[4];
    const float* bfv     = (const float*)d_in[5];
    const float* Uf      = (const float*)d_in[6];
    const float* actor_w = (const float*)d_in[7];
    const float* actor_b = (const float*)d_in[8];
    const float* vmask   = (const float*)d_in[9];

    char* ws = (char*)d_ws;
    bf16*  wtile   = (bf16*)(ws + OFF_WTILE);
    bf16*  wtL     = (bf16*)(ws + OFF_WTL);
    float* biasCat = (float*)(ws + OFF_BIAS);
    bf16*  hA = (bf16*)(ws + OFF_HA);
    bf16*  cA = (bf16*)(ws + OFF_CA);
    bf16*  hB = (bf16*)(ws + OFF_HB);
    bf16*  cB = (bf16*)(ws + OFF_CB);
    bf16*  xL = (bf16*)(ws + OFF_XL);   // aliases hB+cB (dead until L10)

    init_weights<<<dim3((1280 * 640 + 255) / 256), 256, 0, stream>>>(
        Wiou, biou, Uiou, Wf, bfv, Uf, wtile, wtL, biasCat);
    convert_x<<<dim3(8192), 256, 0, stream>>>(arg_hot, xL);

    // leaf level (l=11): m=2048, K=128, reads xL, writes buffers A
    {
        int m = 2048;
        int mtiles = (BATCH * m + 127) / 128;   // 1024
        level_kernel<true><<<dim3(mtiles * 8), 256, 0, stream>>>(
            arg_hot, wtL, biasCat, xL, nullptr, nullptr, hA, cA, m, 11);
    }
    // interior levels 10..0
    for (int l = 10; l >= 0; --l) {
        int m = 1 << l;
        int mtiles = (BATCH * m + 127) / 128;
        bf16 *hc, *cc, *ho, *co;
        if (l & 1) { hc = hB; cc = cB; ho = hA; co = cA; }
        else       { hc = hA; cc = cA; ho = hB; co = cB; }
        level_kernel<false><<<dim3(mtiles * 8), 256, 0, stream>>>(
            arg_hot, wtile, biasCat, nullptr, hc, cc, ho, co, m, l);
    }
    // root h is in hB (level 0 writes B)
    head_kernel<<<dim3(BATCH), 64, 0, stream>>>(hB, actor_w, actor_b, vmask, (float*)d_out);
}